// Round 9
// baseline (310.164 us; speedup 1.0000x reference)
//
#include <hip/hip_runtime.h>
#include <stdint.h>

// B=8, S=2048, H=1024. fp32 in, fp32 out. bf16 MFMA compute core.
#define BD 8
#define SD 2048
#define HD 1024

typedef __bf16 bf16x8 __attribute__((ext_vector_type(8)));
typedef float f32x4 __attribute__((ext_vector_type(4)));
typedef unsigned short u16x8 __attribute__((ext_vector_type(8)));

typedef const __attribute__((address_space(1))) void* gas_ptr;
typedef __attribute__((address_space(3))) void* las_ptr;

__device__ __forceinline__ void gload16(const void* g, void* l) {
  __builtin_amdgcn_global_load_lds((gas_ptr)g, (las_ptr)l, 16, 0, 0);
}

__device__ __forceinline__ unsigned short f32_to_bf16(float f) {
  union { float f; unsigned u; } v; v.f = f;
  unsigned u = v.u;
  return (unsigned short)((u + 0x7FFFu + ((u >> 16) & 1u)) >> 16);  // RNE
}
__device__ __forceinline__ float bf16_to_f32(unsigned short h) {
  union { unsigned u; float f; } v; v.u = ((unsigned)h) << 16;
  return v.f;
}

// ---- cast x: fp32 -> bf16 ----
__global__ __launch_bounds__(256) void cast_x_kernel(
    const float* __restrict__ x, unsigned short* __restrict__ xb) {
  size_t i = (size_t)blockIdx.x * 256 + threadIdx.x;
  const float4* xp = (const float4*)x;
  float4 a = xp[2*i], b = xp[2*i + 1];
  float v[8] = {a.x,a.y,a.z,a.w,b.x,b.y,b.z,b.w};
  u16x8 o;
#pragma unroll
  for (int j = 0; j < 8; j++) o[j] = f32_to_bf16(v[j]);
  *(u16x8*)(xb + i*8) = o;
}

// ---- W [K][N] fp32 -> W^T bf16 [N][K], 3 weights via blockIdx.z ----
__global__ __launch_bounds__(256) void transpose_w_kernel(
    const float* __restrict__ Wq, const float* __restrict__ Wk,
    const float* __restrict__ Wv, unsigned short* __restrict__ wt) {
  __shared__ float tile[32][33];
  const int w = blockIdx.z;
  const float* W = (w == 0) ? Wq : ((w == 1) ? Wk : Wv);
  const int n0 = blockIdx.x * 32, k0 = blockIdx.y * 32;
  const int x = threadIdx.x, y = threadIdx.y;       // block (32,8)
  for (int j = 0; j < 32; j += 8)
    tile[y + j][x] = W[(size_t)(k0 + y + j) * HD + n0 + x];
  __syncthreads();
  unsigned short* dst = wt + (size_t)w * HD * HD;
  for (int j = 0; j < 32; j += 8)
    dst[(size_t)(n0 + y + j) * HD + k0 + x] = f32_to_bf16(tile[x][y + j]);
}

// ---- V [z][2048][1024] bf16 -> Vt [z][1024][2048] bf16 ----
__global__ __launch_bounds__(256) void transpose_v_kernel(
    const unsigned short* __restrict__ V, unsigned short* __restrict__ Vt) {
  __shared__ unsigned short tile[32][33];
  const unsigned short* Vz = V + (size_t)blockIdx.z * SD * HD;
  unsigned short* Vtz = Vt + (size_t)blockIdx.z * HD * SD;
  const int h0 = blockIdx.x * 32, s0 = blockIdx.y * 32;
  const int x = threadIdx.x, y = threadIdx.y;       // block (32,8)
  for (int j = 0; j < 32; j += 8)
    tile[y + j][x] = Vz[(size_t)(s0 + y + j) * HD + h0 + x];
  __syncthreads();
  for (int j = 0; j < 32; j += 8)
    Vtz[(size_t)(h0 + y + j) * SD + s0 + x] = tile[x][y + j];
}

// ---- 256x256 8-phase GEMM (m201-skeleton) ----
// Round-9: (1) MFMA k-outermost — 8 independent MFMAs between each
// dependent acc pair (was k-inner: every adjacent pair dependent);
// (2) ds_reads redistributed 12/8/4/0 per phase (was 16/8/0/0) to smooth
// the LDS pipe (per-CU LDS ~2000cyc/tile vs MFMA 2480 — bursts serialize);
// (3) bf16 epilogue LDS round-trip XOR-swizzled both sides (r8: 1.57M conf).
template<int OUT_BF16>
__global__ __launch_bounds__(512, 2) void gemm256(
    const unsigned short* __restrict__ A, size_t sA,
    const unsigned short* __restrict__ Bt, size_t sB,
    const float* __restrict__ b0, const float* __restrict__ b1,
    const float* __restrict__ b2,
    float* __restrict__ Cf, unsigned short* __restrict__ Cb, size_t sC,
    int M, int N, int K, float alpha)
{
  __shared__ unsigned short As[2 * 256 * 64];   // 64 KB
  __shared__ unsigned short Bs[2 * 256 * 64];   // 64 KB

  // bijective XCD swizzle over flattened grid (all grids % 8 == 0)
  const int gx = gridDim.x, gy = gridDim.y;
  const int nwg = gx * gy * gridDim.z;
  const int flat = blockIdx.x + gx * (blockIdx.y + gy * blockIdx.z);
  const int swz = (flat & 7) * (nwg >> 3) + (flat >> 3);
  const int tz = swz / (gx * gy);
  const int rem = swz - tz * gx * gy;
  const int ty = rem / gx, tx = rem - (rem / gx) * gx;
  const int m0 = ty * 256, n0 = tx * 256;

  A  += (size_t)tz * sA;
  Bt += (size_t)tz * sB;
  const float* bias = (tz == 0) ? b0 : ((tz == 1) ? b1 : b2);

  const int tid = threadIdx.x, lane = tid & 63, w = tid >> 6;  // 8 waves
  const int wr = w >> 2, wc = w & 3;          // 2 x 4 wave grid
  const int nt = K >> 6;                      // BK=64 tiles

  // staging: lane covers row (base + lane>>3), physical 16B slot lane&7;
  // source logical slot = (lane&7) ^ (row&7)  (full-row XOR, r7-verified)
  const int lrow = lane >> 3;
  const int sslot8 = (((lane & 7) ^ ((lane >> 3) & 7)) << 3);

  const int rA = wr * 128 + (lane & 15);
  const int rB = wc * 64 + (lane & 15);
  const int qq = lane >> 4;
  const int sxor = lane & 7;

#define STAGE_A(t,h) do { \
    const unsigned short* _g = A + (size_t)(m0 + (h)*128 + w*16 + lrow) * K + (size_t)((t)*64 + sslot8); \
    unsigned short* _l = &As[((((t)&1)*256 + (h)*128 + w*16)) * 64]; \
    gload16(_g, _l); gload16(_g + (size_t)8*K, _l + 512); } while(0)
#define STAGE_B(t,h) do { \
    const unsigned short* _g = Bt + (size_t)(n0 + (h)*128 + w*16 + lrow) * K + (size_t)((t)*64 + sslot8); \
    unsigned short* _l = &Bs[((((t)&1)*256 + (h)*128 + w*16)) * 64]; \
    gload16(_g, _l); gload16(_g + (size_t)8*K, _l + 512); } while(0)
#define LDA(buf,m,ks) __builtin_bit_cast(bf16x8, *(const u16x8*)(&As[(buf)*16384 + (rA + (m)*16)*64 + ((((ks)*4 + qq) ^ sxor) << 3)]))
#define LDB(buf,n,ks) __builtin_bit_cast(bf16x8, *(const u16x8*)(&Bs[(buf)*16384 + (rB + (n)*16)*64 + ((((ks)*4 + qq) ^ sxor) << 3)]))
// k OUTERMOST: dependent (k0->k1) pairs are 8 MFMAs apart
#define MFMA_Q(AV,MBASE,NLO) \
    _Pragma("unroll") for (int _k = 0; _k < 2; _k++) \
    _Pragma("unroll") for (int _m = 0; _m < 4; _m++) \
    _Pragma("unroll") for (int _n = 0; _n < 2; _n++) \
      acc[(MBASE)+_m][(NLO)+_n] = __builtin_amdgcn_mfma_f32_16x16x32_bf16( \
          AV[_m][_k], bv[(NLO)+_n][_k], acc[(MBASE)+_m][(NLO)+_n], 0, 0, 0);

  f32x4 acc[8][4] = {};
  bf16x8 av0[4][2], av1[4][2], bv[4][2];

  STAGE_B(0,0); STAGE_B(0,1); STAGE_A(0,0); STAGE_A(0,1);
  STAGE_B(1,0); STAGE_B(1,1); STAGE_A(1,0);
  asm volatile("s_waitcnt vmcnt(6)" ::: "memory");
  __builtin_amdgcn_s_barrier();

  for (int t = 0; t < nt; ++t) {
    const int cur = t & 1;
    // ---- phase 0: reads bv01 + av0 (12)
#pragma unroll
    for (int n = 0; n < 2; n++) { bv[n][0] = LDB(cur,n,0); bv[n][1] = LDB(cur,n,1); }
#pragma unroll
    for (int m = 0; m < 4; m++) { av0[m][0] = LDA(cur,m,0); av0[m][1] = LDA(cur,m,1); }
    if (t + 1 < nt) STAGE_A(t+1, 1);
    __builtin_amdgcn_s_barrier();
    __builtin_amdgcn_s_setprio(1);
    MFMA_Q(av0, 0, 0);
    __builtin_amdgcn_s_setprio(0);
    __builtin_amdgcn_s_barrier();
    // ---- phase 1: reads bv23 + av1[0..1] (8)
#pragma unroll
    for (int n = 2; n < 4; n++) { bv[n][0] = LDB(cur,n,0); bv[n][1] = LDB(cur,n,1); }
#pragma unroll
    for (int m = 0; m < 2; m++) { av1[m][0] = LDA(cur,m+4,0); av1[m][1] = LDA(cur,m+4,1); }
    if (t + 2 < nt) STAGE_B(t+2, 0);
    __builtin_amdgcn_s_barrier();
    __builtin_amdgcn_s_setprio(1);
    MFMA_Q(av0, 0, 2);
    __builtin_amdgcn_s_setprio(0);
    __builtin_amdgcn_s_barrier();
    // ---- phase 2: reads av1[2..3] (4)
#pragma unroll
    for (int m = 2; m < 4; m++) { av1[m][0] = LDA(cur,m+4,0); av1[m][1] = LDA(cur,m+4,1); }
    if (t + 2 < nt) STAGE_B(t+2, 1);
    __builtin_amdgcn_s_barrier();
    __builtin_amdgcn_s_setprio(1);
    MFMA_Q(av1, 4, 0);
    __builtin_amdgcn_s_setprio(0);
    __builtin_amdgcn_s_barrier();
    // ---- phase 3: no reads
    if (t + 2 < nt) STAGE_A(t+2, 0);
    __builtin_amdgcn_s_barrier();
    __builtin_amdgcn_s_setprio(1);
    MFMA_Q(av1, 4, 2);
    __builtin_amdgcn_s_setprio(0);
    if (t < nt - 2) asm volatile("s_waitcnt vmcnt(6)" ::: "memory");
    else            asm volatile("s_waitcnt vmcnt(0)" ::: "memory");
    __builtin_amdgcn_s_barrier();
  }

  if (OUT_BF16) {
    // coalesced epilogue via wave-private 16KB LDS slice, XOR-swizzled
    // (slot ^= row&7 on both write and read — kills r8's 1.57M conflicts)
    unsigned short* Cbz = Cb + (size_t)tz * sC;
    unsigned short* base = (w < 4) ? (As + w * 8192) : (Bs + (w - 4) * 8192);
    float bvv[4];
#pragma unroll
    for (int n = 0; n < 4; n++)
      bvv[n] = bias ? bias[n0 + wc * 64 + n * 16 + (lane & 15)] : 0.0f;
#pragma unroll
    for (int n = 0; n < 4; n++)
#pragma unroll
      for (int m = 0; m < 8; m++)
#pragma unroll
        for (int r = 0; r < 4; r++) {
          const int lr = m * 16 + (lane >> 4) * 4 + r;
          const int lc = n * 16 + (lane & 15);
          base[lr * 64 + ((((lc >> 3) ^ (lr & 7)) << 3) | (lc & 7))] =
              f32_to_bf16((acc[m][n][r] + bvv[n]) * alpha);
        }
#pragma unroll
    for (int i = 0; i < 16; i++) {
      const int lr = i * 8 + (lane >> 3);
      u16x8 vrow = *(const u16x8*)(base + lr * 64 + (((lane & 7) ^ (lr & 7)) << 3));
      *(u16x8*)(Cbz + (size_t)(m0 + wr * 128 + lr) * N
                + (n0 + wc * 64 + (lane & 7) * 8)) = vrow;
    }
  } else {
    float* Cfz = Cf + (size_t)tz * sC;
#pragma unroll
    for (int n = 0; n < 4; n++) {
      const int col = n0 + wc * 64 + n * 16 + (lane & 15);
      const float bvv = bias ? bias[col] : 0.0f;
#pragma unroll
      for (int m = 0; m < 8; m++) {
        const int row = m0 + wr * 128 + m * 16 + (lane >> 4) * 4;
#pragma unroll
        for (int r = 0; r < 4; r++)
          Cfz[(size_t)(row + r) * N + col] = (acc[m][n][r] + bvv) * alpha;
      }
    }
  }
#undef STAGE_A
#undef STAGE_B
#undef LDA
#undef LDB
#undef MFMA_Q
}

// ---- in-place row softmax on bf16 scores: S [rows][2048] bf16 ----
__global__ __launch_bounds__(256) void softmax_bf16_kernel(
    unsigned short* __restrict__ S) {
  const int row = blockIdx.x;
  unsigned short* sp = S + (size_t)row * SD;
  const int tid = threadIdx.x, lane = tid & 63, w = tid >> 6;
  u16x8 raw = *(const u16x8*)(sp + tid * 8);
  float x[8];
#pragma unroll
  for (int j = 0; j < 8; j++) x[j] = bf16_to_f32(raw[j]);
  float m = x[0];
#pragma unroll
  for (int j = 1; j < 8; j++) m = fmaxf(m, x[j]);
#pragma unroll
  for (int off = 32; off >= 1; off >>= 1) m = fmaxf(m, __shfl_xor(m, off));
  __shared__ float redm[4];
  if (lane == 0) redm[w] = m;
  __syncthreads();
  m = fmaxf(fmaxf(redm[0], redm[1]), fmaxf(redm[2], redm[3]));
  float e[8]; float s = 0.0f;
#pragma unroll
  for (int j = 0; j < 8; j++) { e[j] = __expf(x[j] - m); s += e[j]; }
#pragma unroll
  for (int off = 32; off >= 1; off >>= 1) s += __shfl_xor(s, off);
  __shared__ float reds[4];
  if (lane == 0) reds[w] = s;
  __syncthreads();
  s = reds[0] + reds[1] + reds[2] + reds[3];
  const float inv = 1.0f / s;
  u16x8 o;
#pragma unroll
  for (int j = 0; j < 8; j++) o[j] = f32_to_bf16(e[j] * inv);
  *(u16x8*)(sp + tid * 8) = o;
}

// ---- launch ----
extern "C" void kernel_launch(void* const* d_in, const int* in_sizes, int n_in,
                              void* d_out, int out_size, void* d_ws, size_t ws_size,
                              hipStream_t stream) {
  const float* x  = (const float*)d_in[0];
  const float* Wq = (const float*)d_in[1];
  const float* bq = (const float*)d_in[2];
  const float* Wk = (const float*)d_in[3];
  const float* bk = (const float*)d_in[4];
  const float* Wv = (const float*)d_in[5];
  const float* bv = (const float*)d_in[6];
  float* out = (float*)d_out;
  char* ws = (char*)d_ws;
  const size_t MB = 1024 * 1024;
  const float scale = 0.03125f;              // 1/sqrt(1024)
  const size_t BH = (size_t)SD * HD;         // 2M elems (one batch of Q/K/V)
  const size_t SS = (size_t)SD * SD;         // 4M elems (one batch of scores)

  // layout: wt 0-6 | Qb 6-38 | Kb 38-70 | Vb 70-102 | xb/Vt 102-134 |
  // scores/P bf16 (in-place softmax) 134-(134 + 8*G) MB
  unsigned short* wt = (unsigned short*)(ws + 0);
  unsigned short* Qb = (unsigned short*)(ws + 6 * MB);
  unsigned short* Kb = (unsigned short*)(ws + 38 * MB);
  unsigned short* Vb = (unsigned short*)(ws + 70 * MB);
  unsigned short* xb = (unsigned short*)(ws + 102 * MB);
  unsigned short* Vt = (unsigned short*)(ws + 102 * MB);   // xb dead by then
  unsigned short* Pb = (unsigned short*)(ws + 134 * MB);   // bf16 scores/P

  int G;
  if      (ws_size >= 198 * MB) G = 8;
  else if (ws_size >= 166 * MB) G = 4;
  else if (ws_size >= 150 * MB) G = 2;
  else                          G = 1;       // needs 142 MB

  transpose_w_kernel<<<dim3(32, 32, 3), dim3(32, 8), 0, stream>>>(Wq, Wk, Wv, wt);
  cast_x_kernel<<<8192, 256, 0, stream>>>(x, xb);

  // fused QKV projection: z = weight index, M = 16384
  gemm256<1><<<dim3(HD/256, (BD*SD)/256, 3), 512, 0, stream>>>(
      xb, 0, wt, (size_t)HD*HD, bq, bk, bv,
      nullptr, Qb, (size_t)16*MB, BD*SD, HD, HD, 1.0f);

  transpose_v_kernel<<<dim3(HD/32, SD/32, BD), dim3(32, 8), 0, stream>>>(Vb, Vt);

  const int ngroups = BD / G;
  for (int g = 0; g < ngroups; g++) {
    // scores = scale * Q K^T  (bf16 out via coalesced epilogue)
    gemm256<1><<<dim3(SD/256, SD/256, G), 512, 0, stream>>>(
        Qb + (size_t)g*G*BH, BH, Kb + (size_t)g*G*BH, BH,
        nullptr, nullptr, nullptr, nullptr, Pb, SS, SD, SD, HD, scale);
    softmax_bf16_kernel<<<G*SD, 256, 0, stream>>>(Pb);
    // out = P V   (fp32 out)
    gemm256<0><<<dim3(HD/256, SD/256, G), 512, 0, stream>>>(
        Pb, SS, Vt + (size_t)g*G*BH, BH, nullptr, nullptr, nullptr,
        out + (size_t)g*G*BH, nullptr, BH, SD, HD, SD, 1.0f);
  }
}

// Round 10
// 295.021 us; speedup vs baseline: 1.0513x; 1.0513x over previous
//
#include <hip/hip_runtime.h>
#include <stdint.h>

// B=8, S=2048, H=1024. fp32 in, fp32 out. bf16 MFMA compute core.
#define BD 8
#define SD 2048
#define HD 1024

typedef __bf16 bf16x8 __attribute__((ext_vector_type(8)));
typedef float f32x4 __attribute__((ext_vector_type(4)));
typedef unsigned short u16x8 __attribute__((ext_vector_type(8)));
typedef unsigned short u16x4 __attribute__((ext_vector_type(4)));

typedef const __attribute__((address_space(1))) void* gas_ptr;
typedef __attribute__((address_space(3))) void* las_ptr;

__device__ __forceinline__ void gload16(const void* g, void* l) {
  __builtin_amdgcn_global_load_lds((gas_ptr)g, (las_ptr)l, 16, 0, 0);
}

__device__ __forceinline__ unsigned short f32_to_bf16(float f) {
  union { float f; unsigned u; } v; v.f = f;
  unsigned u = v.u;
  return (unsigned short)((u + 0x7FFFu + ((u >> 16) & 1u)) >> 16);  // RNE
}
__device__ __forceinline__ float bf16_to_f32(unsigned short h) {
  union { unsigned u; float f; } v; v.u = ((unsigned)h) << 16;
  return v.f;
}

// ---- cast x: fp32 -> bf16 ----
__global__ __launch_bounds__(256) void cast_x_kernel(
    const float* __restrict__ x, unsigned short* __restrict__ xb) {
  size_t i = (size_t)blockIdx.x * 256 + threadIdx.x;
  const float4* xp = (const float4*)x;
  float4 a = xp[2*i], b = xp[2*i + 1];
  float v[8] = {a.x,a.y,a.z,a.w,b.x,b.y,b.z,b.w};
  u16x8 o;
#pragma unroll
  for (int j = 0; j < 8; j++) o[j] = f32_to_bf16(v[j]);
  *(u16x8*)(xb + i*8) = o;
}

// ---- W [K][N] fp32 -> W^T bf16 [N][K], 3 weights via blockIdx.z ----
__global__ __launch_bounds__(256) void transpose_w_kernel(
    const float* __restrict__ Wq, const float* __restrict__ Wk,
    const float* __restrict__ Wv, unsigned short* __restrict__ wt) {
  __shared__ float tile[32][33];
  const int w = blockIdx.z;
  const float* W = (w == 0) ? Wq : ((w == 1) ? Wk : Wv);
  const int n0 = blockIdx.x * 32, k0 = blockIdx.y * 32;
  const int x = threadIdx.x, y = threadIdx.y;       // block (32,8)
  for (int j = 0; j < 32; j += 8)
    tile[y + j][x] = W[(size_t)(k0 + y + j) * HD + n0 + x];
  __syncthreads();
  unsigned short* dst = wt + (size_t)w * HD * HD;
  for (int j = 0; j < 32; j += 8)
    dst[(size_t)(n0 + y + j) * HD + k0 + x] = f32_to_bf16(tile[x][y + j]);
}

// ---- 256x256 8-phase GEMM (r8 main loop — measured fastest) ----
// OUT_MODE: 0 = fp32 row-major; 1 = bf16 row-major (swizzled LDS epilogue);
// 2 = QKV projection: z in {0,1} bf16 row-major, z==2 writes V TRANSPOSED
//     into Vt[b][h][s] via col-major swizzled LDS slice (kills the separate
//     Vb buffer + transpose_v kernel and its 64MB HBM round-trip).
template<int OUT_MODE>
__global__ __launch_bounds__(512, 2) void gemm256(
    const unsigned short* __restrict__ A, size_t sA,
    const unsigned short* __restrict__ Bt, size_t sB,
    const float* __restrict__ b0, const float* __restrict__ b1,
    const float* __restrict__ b2,
    float* __restrict__ Cf, unsigned short* __restrict__ Cb, size_t sC,
    int M, int N, int K, float alpha)
{
  __shared__ unsigned short As[2 * 256 * 64];   // 64 KB
  __shared__ unsigned short Bs[2 * 256 * 64];   // 64 KB

  // bijective XCD swizzle over flattened grid (all grids % 8 == 0)
  const int gx = gridDim.x, gy = gridDim.y;
  const int nwg = gx * gy * gridDim.z;
  const int flat = blockIdx.x + gx * (blockIdx.y + gy * blockIdx.z);
  const int swz = (flat & 7) * (nwg >> 3) + (flat >> 3);
  const int tz = swz / (gx * gy);
  const int rem = swz - tz * gx * gy;
  const int ty = rem / gx, tx = rem - (rem / gx) * gx;
  const int m0 = ty * 256, n0 = tx * 256;

  A  += (size_t)tz * sA;
  Bt += (size_t)tz * sB;
  const float* bias = (tz == 0) ? b0 : ((tz == 1) ? b1 : b2);

  const int tid = threadIdx.x, lane = tid & 63, w = tid >> 6;  // 8 waves
  const int wr = w >> 2, wc = w & 3;          // 2 x 4 wave grid
  const int nt = K >> 6;                      // BK=64 tiles

  // staging: lane covers row (base + lane>>3), physical 16B slot lane&7;
  // source logical slot = (lane&7) ^ (row&7)  (full-row XOR, r7-verified)
  const int lrow = lane >> 3;
  const int sslot8 = (((lane & 7) ^ ((lane >> 3) & 7)) << 3);

  const int rA = wr * 128 + (lane & 15);
  const int rB = wc * 64 + (lane & 15);
  const int qq = lane >> 4;
  const int sxor = lane & 7;

#define STAGE_A(t,h) do { \
    const unsigned short* _g = A + (size_t)(m0 + (h)*128 + w*16 + lrow) * K + (size_t)((t)*64 + sslot8); \
    unsigned short* _l = &As[((((t)&1)*256 + (h)*128 + w*16)) * 64]; \
    gload16(_g, _l); gload16(_g + (size_t)8*K, _l + 512); } while(0)
#define STAGE_B(t,h) do { \
    const unsigned short* _g = Bt + (size_t)(n0 + (h)*128 + w*16 + lrow) * K + (size_t)((t)*64 + sslot8); \
    unsigned short* _l = &Bs[((((t)&1)*256 + (h)*128 + w*16)) * 64]; \
    gload16(_g, _l); gload16(_g + (size_t)8*K, _l + 512); } while(0)
#define LDA(buf,m,ks) __builtin_bit_cast(bf16x8, *(const u16x8*)(&As[(buf)*16384 + (rA + (m)*16)*64 + ((((ks)*4 + qq) ^ sxor) << 3)]))
#define LDB(buf,n,ks) __builtin_bit_cast(bf16x8, *(const u16x8*)(&Bs[(buf)*16384 + (rB + (n)*16)*64 + ((((ks)*4 + qq) ^ sxor) << 3)]))
#define MFMA_Q(AV,MBASE,NLO) \
    _Pragma("unroll") for (int _m = 0; _m < 4; _m++) \
    _Pragma("unroll") for (int _n = 0; _n < 2; _n++) \
    _Pragma("unroll") for (int _k = 0; _k < 2; _k++) \
      acc[(MBASE)+_m][(NLO)+_n] = __builtin_amdgcn_mfma_f32_16x16x32_bf16( \
          AV[_m][_k], bv[(NLO)+_n][_k], acc[(MBASE)+_m][(NLO)+_n], 0, 0, 0);

  f32x4 acc[8][4] = {};
  bf16x8 av0[4][2], av1[4][2], bv[4][2];

  STAGE_B(0,0); STAGE_B(0,1); STAGE_A(0,0); STAGE_A(0,1);
  STAGE_B(1,0); STAGE_B(1,1); STAGE_A(1,0);
  asm volatile("s_waitcnt vmcnt(6)" ::: "memory");
  __builtin_amdgcn_s_barrier();

  for (int t = 0; t < nt; ++t) {
    const int cur = t & 1;
    // ---- phase 0 (reads: all bv + av0)
#pragma unroll
    for (int n = 0; n < 4; n++) { bv[n][0] = LDB(cur,n,0); bv[n][1] = LDB(cur,n,1); }
#pragma unroll
    for (int m = 0; m < 4; m++) { av0[m][0] = LDA(cur,m,0); av0[m][1] = LDA(cur,m,1); }
    if (t + 1 < nt) STAGE_A(t+1, 1);
    __builtin_amdgcn_s_barrier();
    __builtin_amdgcn_s_setprio(1);
    MFMA_Q(av0, 0, 0);
    __builtin_amdgcn_s_setprio(0);
    __builtin_amdgcn_s_barrier();
    // ---- phase 1 (reads: av1)
#pragma unroll
    for (int m = 0; m < 4; m++) { av1[m][0] = LDA(cur,m+4,0); av1[m][1] = LDA(cur,m+4,1); }
    if (t + 2 < nt) STAGE_B(t+2, 0);
    __builtin_amdgcn_s_barrier();
    __builtin_amdgcn_s_setprio(1);
    MFMA_Q(av0, 0, 2);
    __builtin_amdgcn_s_setprio(0);
    __builtin_amdgcn_s_barrier();
    // ---- phase 2
    if (t + 2 < nt) STAGE_B(t+2, 1);
    __builtin_amdgcn_s_barrier();
    __builtin_amdgcn_s_setprio(1);
    MFMA_Q(av1, 4, 0);
    __builtin_amdgcn_s_setprio(0);
    __builtin_amdgcn_s_barrier();
    // ---- phase 3
    if (t + 2 < nt) STAGE_A(t+2, 0);
    __builtin_amdgcn_s_barrier();
    __builtin_amdgcn_s_setprio(1);
    MFMA_Q(av1, 4, 2);
    __builtin_amdgcn_s_setprio(0);
    if (t < nt - 2) asm volatile("s_waitcnt vmcnt(6)" ::: "memory");
    else            asm volatile("s_waitcnt vmcnt(0)" ::: "memory");
    __builtin_amdgcn_s_barrier();
  }

  const bool transposed = (OUT_MODE == 2) && (tz == 2);
  if (OUT_MODE == 0) {
    float* Cfz = Cf + (size_t)tz * sC;
#pragma unroll
    for (int n = 0; n < 4; n++) {
      const int col = n0 + wc * 64 + n * 16 + (lane & 15);
      const float bvv = bias ? bias[col] : 0.0f;
#pragma unroll
      for (int m = 0; m < 8; m++) {
        const int row = m0 + wr * 128 + m * 16 + (lane >> 4) * 4;
#pragma unroll
        for (int r = 0; r < 4; r++)
          Cfz[(size_t)(row + r) * N + col] = (acc[m][n][r] + bvv) * alpha;
      }
    }
  } else if (!transposed) {
    // bf16 row-major via wave-private swizzled LDS slice (r9-verified, 0 conf)
    unsigned short* Cbz = Cb + (size_t)tz * sC;
    unsigned short* base = (w < 4) ? (As + w * 8192) : (Bs + (w - 4) * 8192);
    float bvv[4];
#pragma unroll
    for (int n = 0; n < 4; n++)
      bvv[n] = bias ? bias[n0 + wc * 64 + n * 16 + (lane & 15)] : 0.0f;
#pragma unroll
    for (int n = 0; n < 4; n++)
#pragma unroll
      for (int m = 0; m < 8; m++)
#pragma unroll
        for (int r = 0; r < 4; r++) {
          const int lr = m * 16 + (lane >> 4) * 4 + r;
          const int lc = n * 16 + (lane & 15);
          base[lr * 64 + ((((lc >> 3) ^ (lr & 7)) << 3) | (lc & 7))] =
              f32_to_bf16((acc[m][n][r] + bvv[n]) * alpha);
        }
#pragma unroll
    for (int i = 0; i < 16; i++) {
      const int lr = i * 8 + (lane >> 3);
      u16x8 vrow = *(const u16x8*)(base + lr * 64 + (((lane & 7) ^ (lr & 7)) << 3));
      *(u16x8*)(Cbz + (size_t)(m0 + wr * 128 + lr) * N
                + (n0 + wc * 64 + (lane & 7) * 8)) = vrow;
    }
  } else {
    // V transposed: Vt[b][h][s] = C[b*2048+s][h]. Col-major swizzled LDS
    // slice: elem (col,row) at base[col*128 + (row ^ ((col&7)<<3))].
    // b64 acc-writes (2-way max), b128 row reads (conflict-free), 256B
    // contiguous global segments.
    unsigned short* Vt = Cb + (size_t)2 * sC;
    unsigned short* Vtb = Vt + (size_t)(m0 >> 11) * (HD * SD);
    const int s0 = (m0 & 2047) + wr * 128;
    const int h0 = n0 + wc * 64;
    unsigned short* base = (w < 4) ? (As + w * 8192) : (Bs + (w - 4) * 8192);
    float bvv[4];
#pragma unroll
    for (int n = 0; n < 4; n++)
      bvv[n] = bias ? bias[h0 + n * 16 + (lane & 15)] : 0.0f;
#pragma unroll
    for (int n = 0; n < 4; n++) {
      const int col = n * 16 + (lane & 15);
      const int x = (col & 7) << 3;
#pragma unroll
      for (int m = 0; m < 8; m++) {
        const int row0 = m * 16 + (lane >> 4) * 4;
        u16x4 pk;
#pragma unroll
        for (int r = 0; r < 4; r++)
          pk[r] = f32_to_bf16((acc[m][n][r] + bvv[n]) * alpha);
        *(u16x4*)(base + col * 128 + (row0 ^ x)) = pk;
      }
    }
#pragma unroll
    for (int i = 0; i < 16; i++) {
      const int c = i * 4 + (lane >> 4);
      const int j = lane & 15;
      u16x8 vrow = *(const u16x8*)(base + c * 128 + ((j * 8) ^ ((c & 7) << 3)));
      *(u16x8*)(Vtb + (size_t)(h0 + c) * SD + s0 + j * 8) = vrow;
    }
  }
#undef STAGE_A
#undef STAGE_B
#undef LDA
#undef LDB
#undef MFMA_Q
}

// ---- in-place row softmax on bf16 scores: S [rows][2048] bf16 ----
__global__ __launch_bounds__(256) void softmax_bf16_kernel(
    unsigned short* __restrict__ S) {
  const int row = blockIdx.x;
  unsigned short* sp = S + (size_t)row * SD;
  const int tid = threadIdx.x, lane = tid & 63, w = tid >> 6;
  u16x8 raw = *(const u16x8*)(sp + tid * 8);
  float x[8];
#pragma unroll
  for (int j = 0; j < 8; j++) x[j] = bf16_to_f32(raw[j]);
  float m = x[0];
#pragma unroll
  for (int j = 1; j < 8; j++) m = fmaxf(m, x[j]);
#pragma unroll
  for (int off = 32; off >= 1; off >>= 1) m = fmaxf(m, __shfl_xor(m, off));
  __shared__ float redm[4];
  if (lane == 0) redm[w] = m;
  __syncthreads();
  m = fmaxf(fmaxf(redm[0], redm[1]), fmaxf(redm[2], redm[3]));
  float e[8]; float s = 0.0f;
#pragma unroll
  for (int j = 0; j < 8; j++) { e[j] = __expf(x[j] - m); s += e[j]; }
#pragma unroll
  for (int off = 32; off >= 1; off >>= 1) s += __shfl_xor(s, off);
  __shared__ float reds[4];
  if (lane == 0) reds[w] = s;
  __syncthreads();
  s = reds[0] + reds[1] + reds[2] + reds[3];
  const float inv = 1.0f / s;
  u16x8 o;
#pragma unroll
  for (int j = 0; j < 8; j++) o[j] = f32_to_bf16(e[j] * inv);
  *(u16x8*)(sp + tid * 8) = o;
}

// ---- launch ----
extern "C" void kernel_launch(void* const* d_in, const int* in_sizes, int n_in,
                              void* d_out, int out_size, void* d_ws, size_t ws_size,
                              hipStream_t stream) {
  const float* x  = (const float*)d_in[0];
  const float* Wq = (const float*)d_in[1];
  const float* bq = (const float*)d_in[2];
  const float* Wk = (const float*)d_in[3];
  const float* bk = (const float*)d_in[4];
  const float* Wv = (const float*)d_in[5];
  const float* bv = (const float*)d_in[6];
  float* out = (float*)d_out;
  char* ws = (char*)d_ws;
  const size_t MB = 1024 * 1024;
  const float scale = 0.03125f;              // 1/sqrt(1024)
  const size_t BH = (size_t)SD * HD;         // 2M elems (one batch of Q/K/Vt)
  const size_t SS = (size_t)SD * SD;         // 4M elems (one batch of scores)

  // layout: wt 0-6 | Qb 6-38 | Kb 38-70 | Vt 70-102 (written transposed by
  // proj) | xb 102-134 (dead after proj) | P bf16 overlays xb: 102-(102+8G)
  unsigned short* wt = (unsigned short*)(ws + 0);
  unsigned short* Qb = (unsigned short*)(ws + 6 * MB);
  unsigned short* Kb = (unsigned short*)(ws + 38 * MB);
  unsigned short* Vt = (unsigned short*)(ws + 70 * MB);
  unsigned short* xb = (unsigned short*)(ws + 102 * MB);
  unsigned short* Pb = (unsigned short*)(ws + 102 * MB);   // overlays dead xb

  int G;
  if      (ws_size >= 166 * MB) G = 8;   // P all 8 batches: 102-166
  else if (ws_size >= 134 * MB) G = 4;
  else if (ws_size >= 118 * MB) G = 2;
  else                          G = 1;

  transpose_w_kernel<<<dim3(32, 32, 3), dim3(32, 8), 0, stream>>>(Wq, Wk, Wv, wt);
  cast_x_kernel<<<8192, 256, 0, stream>>>(x, xb);

  // fused QKV projection: z = weight; z==2 writes Vt transposed (OUT_MODE=2)
  gemm256<2><<<dim3(HD/256, (BD*SD)/256, 3), 512, 0, stream>>>(
      xb, 0, wt, (size_t)HD*HD, bq, bk, bv,
      nullptr, Qb, (size_t)16*MB, BD*SD, HD, HD, 1.0f);

  const int ngroups = BD / G;
  for (int g = 0; g < ngroups; g++) {
    // scores = scale * Q K^T  (bf16, coalesced epilogue), z = batch in group
    gemm256<1><<<dim3(SD/256, SD/256, G), 512, 0, stream>>>(
        Qb + (size_t)g*G*BH, BH, Kb + (size_t)g*G*BH, BH,
        nullptr, nullptr, nullptr, nullptr, Pb, SS, SD, SD, HD, scale);
    softmax_bf16_kernel<<<G*SD, 256, 0, stream>>>(Pb);
    // out = P V  (fp32 out); PV at G=8 = 256 blocks -> full machine
    gemm256<0><<<dim3(HD/256, SD/256, G), 512, 0, stream>>>(
        Pb, SS, Vt + (size_t)g*G*BH, BH, nullptr, nullptr, nullptr,
        out + (size_t)g*G*BH, nullptr, BH, SD, HD, SD, 1.0f);
  }
}